// Round 1
// baseline (203.577 us; speedup 1.0000x reference)
//
#include <hip/hip_runtime.h>

#define HORIZON 20
#define BATCH   524288

__global__ __launch_bounds__(256) void drone_rollout(
    const float* __restrict__ state_in,  // [BATCH,16]
    const float* __restrict__ U,         // [HORIZON,1,4] flat = 80
    float* __restrict__ out)             // [HORIZON,BATCH,16]
{
    constexpr float DT    = 0.05f;
    constexpr float MASS  = 1.0f;
    constexpr float GRAV  = 9.81f;
    constexpr float TAU_M = 0.05f;
    constexpr float MAX_T = 5.0f;
    constexpr float ARM   = 0.2f;
    constexpr float KAPPA = 0.02f;
    constexpr float Ix = 0.01f, Iy = 0.01f, Iz = 0.02f;
    const float rIx = 1.0f / Ix, rIy = 1.0f / Iy, rIz = 1.0f / Iz;
    const float dt_tau = DT / TAU_M;   // == 1.0f

    __shared__ float s_act[HORIZON * 4];
    const int tid = threadIdx.x;
    if (tid < HORIZON * 4) {
        float u = U[tid];
        s_act[tid] = 1.0f / (1.0f + expf(-u));
    }
    __syncthreads();

    const int b = blockIdx.x * blockDim.x + tid;

    // Load 16-float state as 4x float4 (64 B/thread).
    const float4* sp = reinterpret_cast<const float4*>(state_in + (size_t)b * 16);
    float4 s0 = sp[0], s1 = sp[1], s2 = sp[2], s3 = sp[3];
    float px = s0.x, py = s0.y, pz = s0.z;
    float vx = s0.w, vy = s1.x, vz = s1.y;
    float phi = s1.z, th = s1.w, psi = s2.x;
    float p = s2.y, q = s2.z, r = s2.w;
    float t0 = s3.x, t1 = s3.y, t2 = s3.z, t3 = s3.w;

    #pragma unroll
    for (int t = 0; t < HORIZON; ++t) {
        const float a0 = s_act[t * 4 + 0];
        const float a1 = s_act[t * 4 + 1];
        const float a2 = s_act[t * 4 + 2];
        const float a3 = s_act[t * 4 + 3];

        // rotor thrust first-order lag (dt_tau == 1, but keep the exact op order)
        t0 += dt_tau * (a0 * MAX_T - t0);
        t1 += dt_tau * (a1 * MAX_T - t1);
        t2 += dt_tau * (a2 * MAX_T - t2);
        t3 += dt_tau * (a3 * MAX_T - t3);

        const float F    = t0 + t1 + t2 + t3;
        const float taux = ARM * (t0 - t2);
        const float tauy = ARM * (t1 - t3);
        const float tauz = KAPPA * (t0 - t1 + t2 - t3);

        float sphi, cphi, sth, cth, spsi, cpsi;
        __sincosf(phi, &sphi, &cphi);
        __sincosf(th,  &sth,  &cth);
        __sincosf(psi, &spsi, &cpsi);

        const float zbx = cphi * sth * cpsi + sphi * spsi;
        const float zby = cphi * sth * spsi - sphi * cpsi;
        const float zbz = cphi * cth;
        const float Fm  = F / MASS;
        const float ax = Fm * zbx;
        const float ay = Fm * zby;
        const float az = Fm * zbz - GRAV;

        const float rcth  = 1.0f / cth;
        const float tanth = sth * rcth;
        const float attd0 = p + sphi * tanth * q + cphi * tanth * r;
        const float attd1 = cphi * q - sphi * r;
        const float attd2 = (sphi * q + cphi * r) * rcth;

        const float hx = Ix * p, hy = Iy * q, hz = Iz * r;
        const float pd = (taux - (q * hz - r * hy)) * rIx;
        const float qd = (tauy - (r * hx - p * hz)) * rIy;
        const float rd = (tauz - (p * hy - q * hx)) * rIz;

        // Euler updates: pos uses old vel; att uses old omega (derivs above).
        px += DT * vx;  py += DT * vy;  pz += DT * vz;
        vx += DT * ax;  vy += DT * ay;  vz += DT * az;
        phi += DT * attd0;  th += DT * attd1;  psi += DT * attd2;
        p += DT * pd;  q += DT * qd;  r += DT * rd;

        float4* op = reinterpret_cast<float4*>(out + ((size_t)t * BATCH + b) * 16);
        op[0] = make_float4(px, py, pz, vx);
        op[1] = make_float4(vy, vz, phi, th);
        op[2] = make_float4(psi, p, q, r);
        op[3] = make_float4(t0, t1, t2, t3);
    }
}

extern "C" void kernel_launch(void* const* d_in, const int* in_sizes, int n_in,
                              void* d_out, int out_size, void* d_ws, size_t ws_size,
                              hipStream_t stream) {
    const float* state = (const float*)d_in[0];
    const float* U     = (const float*)d_in[1];
    float* out         = (float*)d_out;

    dim3 block(256);
    dim3 grid(BATCH / 256);
    drone_rollout<<<grid, block, 0, stream>>>(state, U, out);
}

// Round 3
// 128.727 us; speedup vs baseline: 1.5815x; 1.5815x over previous
//
#include <hip/hip_runtime.h>

#define HORIZON 20
#define BATCH   524288

typedef float f32x4 __attribute__((ext_vector_type(4)));

__global__ __launch_bounds__(256) void drone_rollout(
    const float* __restrict__ state_in,  // [BATCH,16]
    const float* __restrict__ U,         // [HORIZON,1,4] flat = 80
    float* __restrict__ out)             // [HORIZON,BATCH,16]
{
    constexpr float DT    = 0.05f;
    constexpr float GRAV  = 9.81f;
    constexpr float TAU_M = 0.05f;
    constexpr float MAX_T = 5.0f;
    constexpr float ARM   = 0.2f;
    constexpr float KAPPA = 0.02f;
    constexpr float Ix = 0.01f, Iy = 0.01f, Iz = 0.02f;
    const float rIx = 1.0f / Ix, rIy = 1.0f / Iy, rIz = 1.0f / Iz;
    const float dt_tau = DT / TAU_M;   // == 1.0f

    __shared__ float s_act[HORIZON * 4];
    __shared__ f32x4 lds4[2][256 * 4];   // double-buffered 16 KB step buffers

    const int tid = threadIdx.x;
    if (tid < HORIZON * 4) {
        float u = U[tid];
        s_act[tid] = 1.0f / (1.0f + expf(-u));
    }
    __syncthreads();

    const int b = blockIdx.x * blockDim.x + tid;

    // Load 16-float state as 4x f32x4 (64 B/thread; reads are L2-amortized).
    const f32x4* sp = reinterpret_cast<const f32x4*>(state_in + (size_t)b * 16);
    f32x4 s0 = sp[0], s1 = sp[1], s2 = sp[2], s3 = sp[3];
    float px = s0.x, py = s0.y, pz = s0.z;
    float vx = s0.w, vy = s1.x, vz = s1.y;
    float phi = s1.z, th = s1.w, psi = s2.x;
    float p = s2.y, q = s2.z, r = s2.w;
    float t0 = s3.x, t1 = s3.y, t2 = s3.z, t3 = s3.w;

    // Precomputed store geometry.
    const int swzw   = (tid >> 1) & 3;        // write-side chunk XOR
    const int rrow   = tid >> 2;              // read-side base row
    const int rchunk = (tid & 3) ^ ((tid >> 3) & 3);  // read-side swizzled chunk
    f32x4* const outbase = reinterpret_cast<f32x4*>(out)
                         + (size_t)blockIdx.x * 256 * 4;

    #pragma unroll
    for (int t = 0; t < HORIZON; ++t) {
        const float a0 = s_act[t * 4 + 0];
        const float a1 = s_act[t * 4 + 1];
        const float a2 = s_act[t * 4 + 2];
        const float a3 = s_act[t * 4 + 3];

        // rotor thrust first-order lag
        t0 += dt_tau * (a0 * MAX_T - t0);
        t1 += dt_tau * (a1 * MAX_T - t1);
        t2 += dt_tau * (a2 * MAX_T - t2);
        t3 += dt_tau * (a3 * MAX_T - t3);

        const float F    = t0 + t1 + t2 + t3;
        const float taux = ARM * (t0 - t2);
        const float tauy = ARM * (t1 - t3);
        const float tauz = KAPPA * (t0 - t1 + t2 - t3);

        float sphi, cphi, sth, cth, spsi, cpsi;
        __sincosf(phi, &sphi, &cphi);
        __sincosf(th,  &sth,  &cth);
        __sincosf(psi, &spsi, &cpsi);

        const float zbx = cphi * sth * cpsi + sphi * spsi;
        const float zby = cphi * sth * spsi - sphi * cpsi;
        const float zbz = cphi * cth;
        const float ax = F * zbx;          // MASS == 1
        const float ay = F * zby;
        const float az = F * zbz - GRAV;

        const float rcth  = 1.0f / cth;
        const float tanth = sth * rcth;
        const float attd0 = p + sphi * tanth * q + cphi * tanth * r;
        const float attd1 = cphi * q - sphi * r;
        const float attd2 = (sphi * q + cphi * r) * rcth;

        const float hx = Ix * p, hy = Iy * q, hz = Iz * r;
        const float pd = (taux - (q * hz - r * hy)) * rIx;
        const float qd = (tauy - (r * hx - p * hz)) * rIy;
        const float rd = (tauz - (p * hy - q * hx)) * rIz;

        px += DT * vx;  py += DT * vy;  pz += DT * vz;
        vx += DT * ax;  vy += DT * ay;  vz += DT * az;
        phi += DT * attd0;  th += DT * attd1;  psi += DT * attd2;
        p += DT * pd;  q += DT * qd;  r += DT * rd;

        // --- stage this step's state into LDS (swizzled) ---
        const int bb = t & 1;
        f32x4* wb = &lds4[bb][tid * 4];
        wb[0 ^ swzw] = f32x4{px, py, pz, vx};
        wb[1 ^ swzw] = f32x4{vy, vz, phi, th};
        wb[2 ^ swzw] = f32x4{psi, p, q, r};
        wb[3 ^ swzw] = f32x4{t0, t1, t2, t3};
        __syncthreads();

        // --- transposed read-back + lane-contiguous global stores ---
        f32x4* const op = outbase + (size_t)t * (BATCH * 4);
        #pragma unroll
        for (int k = 0; k < 4; ++k) {
            f32x4 v = lds4[bb][(k * 64 + rrow) * 4 + rchunk];
            __builtin_nontemporal_store(v, op + k * 256 + tid);
        }
        // next iteration writes the other buffer; barrier above also
        // protects buffer reuse two steps later
    }
}

extern "C" void kernel_launch(void* const* d_in, const int* in_sizes, int n_in,
                              void* d_out, int out_size, void* d_ws, size_t ws_size,
                              hipStream_t stream) {
    const float* state = (const float*)d_in[0];
    const float* U     = (const float*)d_in[1];
    float* out         = (float*)d_out;

    dim3 block(256);
    dim3 grid(BATCH / 256);
    drone_rollout<<<grid, block, 0, stream>>>(state, U, out);
}